// Round 5
// baseline (145.202 us; speedup 1.0000x reference)
//
#include <hip/hip_runtime.h>

#define HEADS 8
#define HID 128
#define NPB 4       // nodes per 256-thread block (1 wave each)
#define S 8         // counter slices per node (contention spreading)

typedef unsigned short u16;
typedef unsigned int u32;

__device__ __forceinline__ float bf2f(u16 u) { return __uint_as_float(((u32)u) << 16); }
__device__ __forceinline__ u16 f2bf(float f) {
    u32 x = __float_as_uint(f);
    u32 r = (x + 0x7FFF + ((x >> 16) & 1)) >> 16;  // RNE
    return (u16)r;
}

// ---- fused pack (k*0.25,v -> bf16 interleaved rows) + sliced count+rank ----
__global__ void pack_count_kernel(const float* __restrict__ k, const float* __restrict__ v,
                                  const int* __restrict__ ei, u16* __restrict__ kv,
                                  int* __restrict__ counts, int* __restrict__ pos,
                                  int N, int E, int packBlocks) {
    if ((int)blockIdx.x < packBlocks) {
        int g = blockIdx.x * 256 + threadIdx.x;   // node*64 + lane
        int node = g >> 6, l = g & 63;
        if (node < N) {
            float2 kk = ((const float2*)(k + (long long)node * HID))[l];
            float2 vv = ((const float2*)(v + (long long)node * HID))[l];
            ushort4 o;
            o.x = f2bf(kk.x * 0.25f);
            o.y = f2bf(kk.y * 0.25f);
            o.z = f2bf(vv.x);
            o.w = f2bf(vv.y);
            ((ushort4*)(kv + (long long)node * 256))[l] = o;
        }
    } else {
        int e = (blockIdx.x - packBlocks) * 256 + threadIdx.x;
        if (e < E) {
            int slice = (e >> 8) & (S - 1);        // pure function of e
            pos[e] = atomicAdd(&counts[ei[E + e] * S + slice], 1);
        }
    }
}

// ---- scan phase A over M = N*S bins ----
__global__ void scanA_kernel(const int* __restrict__ counts, int* __restrict__ offsets,
                             int* __restrict__ partials, int M) {
    __shared__ int sdata[256];
    int tid = threadIdx.x;
    int base = blockIdx.x * 2048 + tid * 8;
    int v[8];
    int tsum = 0;
    for (int j = 0; j < 8; j++) {
        int idx = base + j;
        v[j] = (idx < M) ? counts[idx] : 0;
        tsum += v[j];
    }
    sdata[tid] = tsum;
    __syncthreads();
    for (int off = 1; off < 256; off <<= 1) {
        int x = sdata[tid];
        int y = (tid >= off) ? sdata[tid - off] : 0;
        __syncthreads();
        sdata[tid] = x + y;
        __syncthreads();
    }
    int excl = sdata[tid] - tsum;
    for (int j = 0; j < 8; j++) {
        int idx = base + j;
        if (idx < M) offsets[idx] = excl;
        excl += v[j];
    }
    if (tid == 255) partials[blockIdx.x] = sdata[255];
}

// ---- scan phase C (B fused) ----
__global__ void scanC_kernel(int* __restrict__ offsets, const int* __restrict__ partials,
                             int M, int E, int nbA) {
    __shared__ int sp[256];
    int tid = threadIdx.x;
    if (tid == 0) {
        int run = 0;
        for (int i = 0; i < nbA; i++) { sp[i] = run; run += partials[i]; }
    }
    __syncthreads();
    int idx = blockIdx.x * blockDim.x + tid;
    if (idx < M) offsets[idx] += sp[idx >> 11];
    if (idx == 0) offsets[M] = E;
}

// ---- fill: atomic-free scatter using precomputed ranks ----
__global__ void fill_kernel(const int* __restrict__ ei, const int* __restrict__ offsets,
                            const int* __restrict__ pos, int* __restrict__ srcs, int E) {
    int e = blockIdx.x * blockDim.x + threadIdx.x;
    if (e < E) {
        int slice = (e >> 8) & (S - 1);
        srcs[offsets[ei[E + e] * S + slice] + pos[e]] = ei[e];
    }
}

// ---- per-node reduction, packed bf16 kv rows, 8-deep unroll ----
__global__ __launch_bounds__(256) void reduce_packed(
        const float* __restrict__ q, const u16* __restrict__ kv,
        const int* __restrict__ offsets, const int* __restrict__ srcs,
        float* __restrict__ out, int N) {
    int node = blockIdx.x * NPB + (threadIdx.x >> 6);
    if (node >= N) return;
    int l = threadIdx.x & 63;

    float2 qv = ((const float2*)(q + (long long)node * HID))[l];
    const ushort4* kv4 = (const ushort4*)kv;
    float accx = 0.0f, accy = 0.0f, z = 0.0f;

    int beg = offsets[node * S];
    int end = offsets[node * S + S];
    int i = beg;

    for (; i + 8 <= end; i += 8) {
        int s0 = srcs[i + 0], s1 = srcs[i + 1], s2 = srcs[i + 2], s3 = srcs[i + 3];
        int s4 = srcs[i + 4], s5 = srcs[i + 5], s6 = srcs[i + 6], s7 = srcs[i + 7];
        ushort4 a0 = kv4[(long long)s0 * 64 + l];
        ushort4 a1 = kv4[(long long)s1 * 64 + l];
        ushort4 a2 = kv4[(long long)s2 * 64 + l];
        ushort4 a3 = kv4[(long long)s3 * 64 + l];
        ushort4 a4 = kv4[(long long)s4 * 64 + l];
        ushort4 a5 = kv4[(long long)s5 * 64 + l];
        ushort4 a6 = kv4[(long long)s6 * 64 + l];
        ushort4 a7 = kv4[(long long)s7 * 64 + l];

        float p0 = bf2f(a0.x) * qv.x + bf2f(a0.y) * qv.y;
        float p1 = bf2f(a1.x) * qv.x + bf2f(a1.y) * qv.y;
        float p2 = bf2f(a2.x) * qv.x + bf2f(a2.y) * qv.y;
        float p3 = bf2f(a3.x) * qv.x + bf2f(a3.y) * qv.y;
        float p4 = bf2f(a4.x) * qv.x + bf2f(a4.y) * qv.y;
        float p5 = bf2f(a5.x) * qv.x + bf2f(a5.y) * qv.y;
        float p6 = bf2f(a6.x) * qv.x + bf2f(a6.y) * qv.y;
        float p7 = bf2f(a7.x) * qv.x + bf2f(a7.y) * qv.y;

        p0 += __shfl_xor(p0, 1); p1 += __shfl_xor(p1, 1);
        p2 += __shfl_xor(p2, 1); p3 += __shfl_xor(p3, 1);
        p4 += __shfl_xor(p4, 1); p5 += __shfl_xor(p5, 1);
        p6 += __shfl_xor(p6, 1); p7 += __shfl_xor(p7, 1);
        p0 += __shfl_xor(p0, 2); p1 += __shfl_xor(p1, 2);
        p2 += __shfl_xor(p2, 2); p3 += __shfl_xor(p3, 2);
        p4 += __shfl_xor(p4, 2); p5 += __shfl_xor(p5, 2);
        p6 += __shfl_xor(p6, 2); p7 += __shfl_xor(p7, 2);
        p0 += __shfl_xor(p0, 4); p1 += __shfl_xor(p1, 4);
        p2 += __shfl_xor(p2, 4); p3 += __shfl_xor(p3, 4);
        p4 += __shfl_xor(p4, 4); p5 += __shfl_xor(p5, 4);
        p6 += __shfl_xor(p6, 4); p7 += __shfl_xor(p7, 4);

        float c0 = __expf(fminf(fmaxf(p0, -5.0f), 5.0f));
        float c1 = __expf(fminf(fmaxf(p1, -5.0f), 5.0f));
        float c2 = __expf(fminf(fmaxf(p2, -5.0f), 5.0f));
        float c3 = __expf(fminf(fmaxf(p3, -5.0f), 5.0f));
        float c4 = __expf(fminf(fmaxf(p4, -5.0f), 5.0f));
        float c5 = __expf(fminf(fmaxf(p5, -5.0f), 5.0f));
        float c6 = __expf(fminf(fmaxf(p6, -5.0f), 5.0f));
        float c7 = __expf(fminf(fmaxf(p7, -5.0f), 5.0f));

        accx += bf2f(a0.z) * c0 + bf2f(a1.z) * c1 + bf2f(a2.z) * c2 + bf2f(a3.z) * c3
              + bf2f(a4.z) * c4 + bf2f(a5.z) * c5 + bf2f(a6.z) * c6 + bf2f(a7.z) * c7;
        accy += bf2f(a0.w) * c0 + bf2f(a1.w) * c1 + bf2f(a2.w) * c2 + bf2f(a3.w) * c3
              + bf2f(a4.w) * c4 + bf2f(a5.w) * c5 + bf2f(a6.w) * c6 + bf2f(a7.w) * c7;
        z += c0 + c1 + c2 + c3 + c4 + c5 + c6 + c7;
    }
    for (; i < end; i++) {
        int s = srcs[i];
        ushort4 a = kv4[(long long)s * 64 + l];
        float p = bf2f(a.x) * qv.x + bf2f(a.y) * qv.y;
        p += __shfl_xor(p, 1);
        p += __shfl_xor(p, 2);
        p += __shfl_xor(p, 4);
        float c = __expf(fminf(fmaxf(p, -5.0f), 5.0f));
        accx += bf2f(a.z) * c;
        accy += bf2f(a.w) * c;
        z += c;
    }
    float inv = 1.0f / (z + 1e-6f);
    ((float2*)(out + (long long)node * HID))[l] = make_float2(accx * inv, accy * inv);
}

// ---- fallback reduction (fp32 gathers) if workspace too small for pack ----
__global__ __launch_bounds__(256) void reduce_f32(
        const float* __restrict__ q, const float* __restrict__ k,
        const float* __restrict__ v, const int* __restrict__ offsets,
        const int* __restrict__ srcs, float* __restrict__ out, int N) {
    int node = blockIdx.x * NPB + (threadIdx.x >> 6);
    if (node >= N) return;
    int l = threadIdx.x & 63;
    float2 qv = ((const float2*)(q + (long long)node * HID))[l];
    float accx = 0.0f, accy = 0.0f, z = 0.0f;
    int beg = offsets[node * S], end = offsets[node * S + S];
    for (int i = beg; i < end; i++) {
        int s = srcs[i];
        float2 kk = ((const float2*)(k + (long long)s * HID))[l];
        float2 vv = ((const float2*)(v + (long long)s * HID))[l];
        float p = (kk.x * qv.x + kk.y * qv.y) * 0.25f;
        p += __shfl_xor(p, 1);
        p += __shfl_xor(p, 2);
        p += __shfl_xor(p, 4);
        float c = __expf(fminf(fmaxf(p, -5.0f), 5.0f));
        accx += vv.x * c; accy += vv.y * c; z += c;
    }
    float inv = 1.0f / (z + 1e-6f);
    ((float2*)(out + (long long)node * HID))[l] = make_float2(accx * inv, accy * inv);
}

extern "C" void kernel_launch(void* const* d_in, const int* in_sizes, int n_in,
                              void* d_out, int out_size, void* d_ws, size_t ws_size,
                              hipStream_t stream) {
    const float* q = (const float*)d_in[0];
    const float* k = (const float*)d_in[1];
    const float* v = (const float*)d_in[2];
    const int* ei = (const int*)d_in[3];
    float* out = (float*)d_out;

    int E = in_sizes[3] / 2;      // 800000
    int N = in_sizes[0] / HID;    // 50000
    int M = N * S;                // sliced bins

    int block = 256;
    int eblocks = (E + block - 1) / block;
    int nbA = (M + 2047) / 2048;           // <= 256 enforced by sp[] size (196 here)
    int nblocksM = (M + 255) / 256;
    int rgrid = (N + NPB - 1) / NPB;

    size_t kv_bytes = (size_t)N * 256 * sizeof(u16);
    size_t tail_ints = (size_t)M + (size_t)M + 1 + 256 + 2 * (size_t)E;
    size_t need_packed = kv_bytes + tail_ints * 4 + 64;

    if (ws_size >= need_packed) {
        u16* kv = (u16*)d_ws;
        int* counts = (int*)((char*)d_ws + kv_bytes);
        int* offsets = counts + M;
        int* partials = offsets + M + 1;
        int* pos = partials + 256;
        int* srcs = pos + E;

        hipMemsetAsync(counts, 0, (size_t)M * sizeof(int), stream);

        int packBlocks = (N * 64 + block - 1) / block;
        pack_count_kernel<<<packBlocks + eblocks, block, 0, stream>>>(
            k, v, ei, kv, counts, pos, N, E, packBlocks);
        scanA_kernel<<<nbA, block, 0, stream>>>(counts, offsets, partials, M);
        scanC_kernel<<<nblocksM, block, 0, stream>>>(offsets, partials, M, E, nbA);
        fill_kernel<<<eblocks, block, 0, stream>>>(ei, offsets, pos, srcs, E);
        reduce_packed<<<rgrid, block, 0, stream>>>(q, kv, offsets, srcs, out, N);
    } else {
        int* counts = (int*)d_ws;
        int* offsets = counts + M;
        int* partials = offsets + M + 1;
        int* pos = partials + 256;
        int* srcs = pos + E;

        hipMemsetAsync(counts, 0, (size_t)M * sizeof(int), stream);
        pack_count_kernel<<<eblocks, block, 0, stream>>>(
            k, v, ei, (u16*)nullptr, counts, pos, N, E, 0);
        scanA_kernel<<<nbA, block, 0, stream>>>(counts, offsets, partials, M);
        scanC_kernel<<<nblocksM, block, 0, stream>>>(offsets, partials, M, E, nbA);
        fill_kernel<<<eblocks, block, 0, stream>>>(ei, offsets, pos, srcs, E);
        reduce_f32<<<rgrid, block, 0, stream>>>(q, k, v, offsets, srcs, out, N);
    }
}